// Round 1
// baseline (531.779 us; speedup 1.0000x reference)
//
#include <hip/hip_runtime.h>
#include <math.h>

#define NLEV 16

typedef _Float16 f16;
typedef f16 f16x8 __attribute__((ext_vector_type(8)));
typedef float f32x4 __attribute__((ext_vector_type(4)));

struct LevelMeta {
    float scale[NLEV];
    int   r1[NLEV];    // grid row stride = r+1
    int   off[NLEV];   // element offset into embeddings table
};

// LDS budget: w0s 5120B + w1s 9216B + w2s 2304B + wbuf 36864B = 53504B (<64KB static, 3 WG/CU)
__global__ __launch_bounds__(256, 3)
void hashmlp_kernel(const float* __restrict__ x,
                    const float* __restrict__ cmax,
                    const float* __restrict__ emb,
                    const float* __restrict__ w0,
                    const float* __restrict__ b0,
                    const float* __restrict__ w1,
                    const float* __restrict__ b1,
                    const float* __restrict__ w2,
                    const float* __restrict__ b2,
                    float* __restrict__ out,
                    int npts,
                    LevelMeta meta)
{
    __shared__ f16 w0s[64 * 40];   // [n=64][k=32] pad->40
    __shared__ f16 w1s[64 * 72];   // [n=64][k=64] pad->72
    __shared__ f16 w2s[16 * 72];   // [n=16][k=64] pad->72 (rows 3..15 zero)
    __shared__ f16 wbuf[4][4608];  // per-wave: feats [64][40] then h [64][72] (9216B)

    const int tid  = threadIdx.x;
    const int lane = tid & 63;
    const int wave = tid >> 6;

    // ---- stage MLP weights as f16 (once per block) ----
    for (int i = tid; i < 64 * 32; i += 256)
        w0s[(i >> 5) * 40 + (i & 31)] = (f16)w0[i];
    for (int i = tid; i < 64 * 64; i += 256)
        w1s[(i >> 6) * 72 + (i & 63)] = (f16)w1[i];
    for (int i = tid; i < 16 * 64; i += 256) {
        int r = i >> 6, c = i & 63;
        w2s[r * 72 + c] = (r < 3) ? (f16)w2[r * 64 + c] : (f16)0.f;
    }
    __syncthreads();

    // ---- hashgrid encode (fp32, per thread = one point) ----
    const int p = blockIdx.x * 256 + tid;
    const float2 xy = ((const float2*)x)[p];
    const float x0 = xy.x / cmax[1];   // x01 = x / cmax[::-1]
    const float x1 = xy.y / cmax[0];
    const float2* emb2 = (const float2*)emb;

    float fr[32];
#pragma unroll
    for (int l = 0; l < NLEV; ++l) {
        const float sc = meta.scale[l];
        const int r1 = meta.r1[l];
        const int off = meta.off[l];
        float p0 = x0 * sc + 0.5f;
        float p1 = x1 * sc + 0.5f;
        float g0 = floorf(p0), g1 = floorf(p1);
        float f0 = p0 - g0, f1 = p1 - g1;
        int i0 = (int)g0, i1 = (int)g1;
        const float2* eb = emb2 + (off + i1 * r1 + i0);
        float2 e00 = eb[0];
        float2 e10 = eb[1];
        float2 e01 = eb[r1];
        float2 e11 = eb[r1 + 1];
        float omf0 = 1.f - f0, omf1 = 1.f - f1;
        float w00 = omf0 * omf1, w01 = omf0 * f1, w10 = f0 * omf1, w11 = f0 * f1;
        // reference corner order: (0,0),(0,1),(1,0),(1,1)
        float a0 = w00 * e00.x; a0 += w01 * e01.x; a0 += w10 * e10.x; a0 += w11 * e11.x;
        float a1 = w00 * e00.y; a1 += w01 * e01.y; a1 += w10 * e10.y; a1 += w11 * e11.y;
        fr[2 * l]     = a0;
        fr[2 * l + 1] = a1;
    }

    // ---- write out_lc0 (fp32, exact) ----
    float* outlc = out + (size_t)npts * 3 + (size_t)p * 32;
#pragma unroll
    for (int c = 0; c < 8; ++c) {
        float4 v;
        v.x = fr[4 * c]; v.y = fr[4 * c + 1]; v.z = fr[4 * c + 2]; v.w = fr[4 * c + 3];
        ((float4*)outlc)[c] = v;
    }

    // ---- stage relu(feats)*2^14 as f16 into per-wave LDS [64][40] ----
    f16* fbuf = wbuf[wave];
#pragma unroll
    for (int c = 0; c < 4; ++c) {
        f16x8 v;
#pragma unroll
        for (int j = 0; j < 8; ++j)
            v[j] = (f16)(fmaxf(fr[8 * c + j], 0.f) * 16384.f);
        *(f16x8*)&fbuf[lane * 40 + c * 8] = v;
    }

    const int lr = lane & 15;   // row/col within 16-tile
    const int lg = lane >> 4;   // k-group
    f16* hbuf = wbuf[wave];     // reused buffer: feats -> h1 -> h2

    // ---- layer 0: [64pts x 32] @ w0^T -> h1 [64 x 64] ----
    {
        f16x8 bf[4];
        float bia[4];
#pragma unroll
        for (int nt = 0; nt < 4; ++nt) {
            bf[nt] = *(const f16x8*)&w0s[(nt * 16 + lr) * 40 + lg * 8];
            bia[nt] = b0[nt * 16 + lr];
        }
        // descending mt so h1 writes never clobber unread feats rows
#pragma unroll
        for (int mt = 3; mt >= 0; --mt) {
            f16x8 a = *(const f16x8*)&fbuf[(mt * 16 + lr) * 40 + lg * 8];
#pragma unroll
            for (int nt = 0; nt < 4; ++nt) {
                f32x4 c = {0.f, 0.f, 0.f, 0.f};
                c = __builtin_amdgcn_mfma_f32_16x16x32_f16(a, bf[nt], c, 0, 0, 0);
#pragma unroll
                for (int q = 0; q < 4; ++q) {
                    float h = fmaxf(c[q] * (1.0f / 16384.f) + bia[nt], 0.f);
                    hbuf[(mt * 16 + lg * 4 + q) * 72 + nt * 16 + lr] = (f16)h;
                }
            }
        }
    }

    // ---- layer 1: h1 @ w1^T -> h2 [64 x 64] (in-place rows per mt) ----
    {
        f16x8 bf[4][2];
        float bia[4];
#pragma unroll
        for (int nt = 0; nt < 4; ++nt) {
            bf[nt][0] = *(const f16x8*)&w1s[(nt * 16 + lr) * 72 + lg * 8];
            bf[nt][1] = *(const f16x8*)&w1s[(nt * 16 + lr) * 72 + 32 + lg * 8];
            bia[nt] = b1[nt * 16 + lr];
        }
#pragma unroll
        for (int mt = 0; mt < 4; ++mt) {
            f16x8 a0 = *(const f16x8*)&hbuf[(mt * 16 + lr) * 72 + lg * 8];
            f16x8 a1 = *(const f16x8*)&hbuf[(mt * 16 + lr) * 72 + 32 + lg * 8];
#pragma unroll
            for (int nt = 0; nt < 4; ++nt) {
                f32x4 c = {0.f, 0.f, 0.f, 0.f};
                c = __builtin_amdgcn_mfma_f32_16x16x32_f16(a0, bf[nt][0], c, 0, 0, 0);
                c = __builtin_amdgcn_mfma_f32_16x16x32_f16(a1, bf[nt][1], c, 0, 0, 0);
#pragma unroll
                for (int q = 0; q < 4; ++q) {
                    float h = fmaxf(c[q] + bia[nt], 0.f);
                    hbuf[(mt * 16 + lg * 4 + q) * 72 + nt * 16 + lr] = (f16)h;
                }
            }
        }
    }

    // ---- layer 2: h2 @ w2^T + b2 -> out [64 x 3] ----
    {
        f16x8 bf0 = *(const f16x8*)&w2s[lr * 72 + lg * 8];
        f16x8 bf1 = *(const f16x8*)&w2s[lr * 72 + 32 + lg * 8];
        float bia2 = (lr < 3) ? b2[lr] : 0.f;
        const int pbase = blockIdx.x * 256 + wave * 64;
#pragma unroll
        for (int mt = 0; mt < 4; ++mt) {
            f16x8 a0 = *(const f16x8*)&hbuf[(mt * 16 + lr) * 72 + lg * 8];
            f16x8 a1 = *(const f16x8*)&hbuf[(mt * 16 + lr) * 72 + 32 + lg * 8];
            f32x4 c = {0.f, 0.f, 0.f, 0.f};
            c = __builtin_amdgcn_mfma_f32_16x16x32_f16(a0, bf0, c, 0, 0, 0);
            c = __builtin_amdgcn_mfma_f32_16x16x32_f16(a1, bf1, c, 0, 0, 0);
            if (lr < 3) {
#pragma unroll
                for (int q = 0; q < 4; ++q) {
                    out[(size_t)(pbase + mt * 16 + lg * 4 + q) * 3 + lr] = c[q] + bia2;
                }
            }
        }
    }
}

extern "C" void kernel_launch(void* const* d_in, const int* in_sizes, int n_in,
                              void* d_out, int out_size, void* d_ws, size_t ws_size,
                              hipStream_t stream) {
    const float* x    = (const float*)d_in[0];
    const float* cmax = (const float*)d_in[1];
    const float* emb  = (const float*)d_in[2];
    const float* w0   = (const float*)d_in[3];
    const float* b0   = (const float*)d_in[4];
    const float* w1   = (const float*)d_in[5];
    const float* b1   = (const float*)d_in[6];
    const float* w2   = (const float*)d_in[7];
    const float* b2   = (const float*)d_in[8];
    const int npts = in_sizes[0] / 2;

    // torch-ngp gridencoder level geometry, same double-precision math as the reference
    LevelMeta meta;
    const double S = log2(2048.0 / 16.0) / 15.0;
    long long off = 0;
    for (int l = 0; l < NLEV; ++l) {
        double s = pow(2.0, l * S) * 16.0 - 1.0;
        int r = (int)ceil(s) + 1;
        long long pc = (long long)(r + 1) * (r + 1);
        if (pc > (1ll << 24)) pc = (1ll << 24);
        pc = ((pc + 7) / 8) * 8;
        meta.scale[l] = (float)s;
        meta.r1[l]    = r + 1;
        meta.off[l]   = (int)off;
        off += pc;
    }

    const int blocks = npts / 256;
    hipLaunchKernelGGL(hashmlp_kernel, dim3(blocks), dim3(256), 0, stream,
                       x, cmax, emb, w0, b0, w1, b1, w2, b2, (float*)d_out, npts, meta);
}

// Round 3
// 523.887 us; speedup vs baseline: 1.0151x; 1.0151x over previous
//
#include <hip/hip_runtime.h>
#include <math.h>

#define NLEV 16
#define NBIN 4096   // 64x64 Morton bins

typedef _Float16 f16;
typedef f16 f16x8 __attribute__((ext_vector_type(8)));
typedef float f32x4 __attribute__((ext_vector_type(4)));

struct LevelMeta {
    float scale[NLEV];
    int   r1[NLEV];    // grid row stride = r+1
    int   off[NLEV];   // element offset into embeddings table
};

// 2D bit-interleave: spread 6-bit v to even bit positions (0,2,4,6,8,10)
__device__ inline unsigned spread2d(unsigned v) {
    v = (v | (v << 4)) & 0x0F0Fu;
    v = (v | (v << 2)) & 0x3333u;
    v = (v | (v << 1)) & 0x5555u;
    return v;
}

__device__ inline unsigned bin_of(float x0, float x1) {
    int bx = (int)(x0 * 64.f); bx = bx < 0 ? 0 : (bx > 63 ? 63 : bx);
    int by = (int)(x1 * 64.f); by = by < 0 ? 0 : (by > 63 ? 63 : by);
    return spread2d((unsigned)bx) | (spread2d((unsigned)by) << 1);  // [0, 4096)
}

// ---- pass 0: zero the histogram (deterministic, graph-safe) ----
__global__ __launch_bounds__(256)
void zero_kernel(unsigned* __restrict__ hist) {
    ((uint4*)hist)[threadIdx.x * 4 + 0] = uint4{0, 0, 0, 0};
    ((uint4*)hist)[threadIdx.x * 4 + 1] = uint4{0, 0, 0, 0};
    ((uint4*)hist)[threadIdx.x * 4 + 2] = uint4{0, 0, 0, 0};
    ((uint4*)hist)[threadIdx.x * 4 + 3] = uint4{0, 0, 0, 0};
}

// ---- pass 1: per-bin histogram ----
__global__ __launch_bounds__(256)
void hist_kernel(const float* __restrict__ x, const float* __restrict__ cmax,
                 unsigned* __restrict__ hist) {
    int p = blockIdx.x * 256 + threadIdx.x;
    float2 xy = ((const float2*)x)[p];
    float x0 = xy.x / cmax[1];
    float x1 = xy.y / cmax[0];
    atomicAdd(&hist[bin_of(x0, x1)], 1u);
}

// ---- pass 2: exclusive prefix scan of 4096 bins (one block) ----
__global__ __launch_bounds__(256)
void scan_kernel(const unsigned* __restrict__ hist, unsigned* __restrict__ base) {
    __shared__ unsigned wsum[4];
    int t = threadIdx.x;
    unsigned v[16];
    unsigned s = 0;
#pragma unroll
    for (int k = 0; k < 4; ++k) {
        uint4 h = ((const uint4*)hist)[t * 4 + k];
        v[4 * k] = h.x; v[4 * k + 1] = h.y; v[4 * k + 2] = h.z; v[4 * k + 3] = h.w;
        s += h.x + h.y + h.z + h.w;
    }
    int lane = t & 63, w = t >> 6;
    unsigned xs = s;
#pragma unroll
    for (int off = 1; off < 64; off <<= 1) {
        unsigned y = (unsigned)__shfl_up((int)xs, off);
        if (lane >= off) xs += y;
    }
    if (lane == 63) wsum[w] = xs;
    __syncthreads();
    unsigned wo = 0;
    for (int k = 0; k < w; ++k) wo += wsum[k];
    unsigned run = wo + xs - s;  // exclusive prefix for this thread's chunk
#pragma unroll
    for (int j = 0; j < 16; ++j) {
        base[t * 16 + j] = run;
        run += v[j];
    }
}

// ---- pass 3: scatter into sorted order ----
__global__ __launch_bounds__(256)
void scatter_kernel(const float* __restrict__ x, const float* __restrict__ cmax,
                    unsigned* __restrict__ base, unsigned* __restrict__ pidx,
                    float2* __restrict__ px) {
    int p = blockIdx.x * 256 + threadIdx.x;
    float2 xy = ((const float2*)x)[p];
    float x0 = xy.x / cmax[1];
    float x1 = xy.y / cmax[0];
    unsigned rank = atomicAdd(&base[bin_of(x0, x1)], 1u);
    pidx[rank] = (unsigned)p;
    float2 v; v.x = x0; v.y = x1;
    px[rank] = v;
}

// ---- pass 4: fused hashgrid + MLP ----
// LDS: w0s 5120B + w1s 9216B + w2s 2304B + wbuf 36864B = 53504B -> 3 WG/CU
__global__ __launch_bounds__(256, 3)
void hashmlp_kernel(const float* __restrict__ x,
                    const float* __restrict__ cmax,
                    const unsigned* __restrict__ pidx,   // may be null (fallback)
                    const float2* __restrict__ px,       // may be null
                    const float* __restrict__ emb,
                    const float* __restrict__ w0,
                    const float* __restrict__ b0,
                    const float* __restrict__ w1,
                    const float* __restrict__ b1,
                    const float* __restrict__ w2,
                    const float* __restrict__ b2,
                    float* __restrict__ out,
                    int npts, int nblk,
                    LevelMeta meta)
{
    __shared__ f16 w0s[64 * 40];
    __shared__ f16 w1s[64 * 72];
    __shared__ f16 w2s[16 * 72];
    __shared__ f16 wbuf[4][4608];

    const int tid  = threadIdx.x;
    const int lane = tid & 63;
    const int wave = tid >> 6;

    for (int i = tid; i < 64 * 32; i += 256)
        w0s[(i >> 5) * 40 + (i & 31)] = (f16)w0[i];
    for (int i = tid; i < 64 * 64; i += 256)
        w1s[(i >> 6) * 72 + (i & 63)] = (f16)w1[i];
    for (int i = tid; i < 16 * 64; i += 256) {
        int r = i >> 6, c = i & 63;
        w2s[r * 72 + c] = (r < 3) ? (f16)w2[r * 64 + c] : (f16)0.f;
    }
    __syncthreads();

    // XCD-chunked swizzle: contiguous sorted (spatial) range per XCD
    int bid = blockIdx.x;
    int cpx = nblk >> 3;                       // nblk divisible by 8
    int swz = (bid & 7) * cpx + (bid >> 3);
    const int g = swz * 256 + tid;             // sorted slot
    const int gblk = swz * 256 + wave * 64;    // wave's first sorted slot

    int p;          // original point index (output location)
    float x0, x1;
    if (pidx) {
        p = (int)pidx[g];
        float2 xy = px[g];
        x0 = xy.x; x1 = xy.y;
    } else {
        p = g;
        float2 xy = ((const float2*)x)[p];
        x0 = xy.x / cmax[1];
        x1 = xy.y / cmax[0];
    }
    const float2* emb2 = (const float2*)emb;

    float fr[32];
#pragma unroll
    for (int l = 0; l < NLEV; ++l) {
        const float sc = meta.scale[l];
        const int r1 = meta.r1[l];
        const int off = meta.off[l];
        float p0 = x0 * sc + 0.5f;
        float p1 = x1 * sc + 0.5f;
        float g0 = floorf(p0), g1 = floorf(p1);
        float f0 = p0 - g0, f1 = p1 - g1;
        int i0 = (int)g0, i1 = (int)g1;
        const float2* eb = emb2 + (off + i1 * r1 + i0);
        float2 e00 = eb[0];
        float2 e10 = eb[1];
        float2 e01 = eb[r1];
        float2 e11 = eb[r1 + 1];
        float omf0 = 1.f - f0, omf1 = 1.f - f1;
        float w00 = omf0 * omf1, w01 = omf0 * f1, w10 = f0 * omf1, w11 = f0 * f1;
        float a0 = w00 * e00.x; a0 += w01 * e01.x; a0 += w10 * e10.x; a0 += w11 * e11.x;
        float a1 = w00 * e00.y; a1 += w01 * e01.y; a1 += w10 * e10.y; a1 += w11 * e11.y;
        fr[2 * l]     = a0;
        fr[2 * l + 1] = a1;
    }

    // out_lc0 (fp32, exact) at original position
    float* outlc = out + (size_t)npts * 3 + (size_t)p * 32;
#pragma unroll
    for (int c = 0; c < 8; ++c) {
        float4 v;
        v.x = fr[4 * c]; v.y = fr[4 * c + 1]; v.z = fr[4 * c + 2]; v.w = fr[4 * c + 3];
        ((float4*)outlc)[c] = v;
    }

    // stage relu(feats)*2^14 as f16 into per-wave LDS [64][40]
    f16* fbuf = wbuf[wave];
#pragma unroll
    for (int c = 0; c < 4; ++c) {
        f16x8 v;
#pragma unroll
        for (int j = 0; j < 8; ++j)
            v[j] = (f16)(fmaxf(fr[8 * c + j], 0.f) * 16384.f);
        *(f16x8*)&fbuf[lane * 40 + c * 8] = v;
    }

    const int lr = lane & 15;
    const int lg = lane >> 4;
    f16* hbuf = wbuf[wave];

    // layer 0
    {
        f16x8 bf[4];
        float bia[4];
#pragma unroll
        for (int nt = 0; nt < 4; ++nt) {
            bf[nt] = *(const f16x8*)&w0s[(nt * 16 + lr) * 40 + lg * 8];
            bia[nt] = b0[nt * 16 + lr];
        }
#pragma unroll
        for (int mt = 3; mt >= 0; --mt) {
            f16x8 a = *(const f16x8*)&fbuf[(mt * 16 + lr) * 40 + lg * 8];
#pragma unroll
            for (int nt = 0; nt < 4; ++nt) {
                f32x4 c = {0.f, 0.f, 0.f, 0.f};
                c = __builtin_amdgcn_mfma_f32_16x16x32_f16(a, bf[nt], c, 0, 0, 0);
#pragma unroll
                for (int q = 0; q < 4; ++q) {
                    float h = fmaxf(c[q] * (1.0f / 16384.f) + bia[nt], 0.f);
                    hbuf[(mt * 16 + lg * 4 + q) * 72 + nt * 16 + lr] = (f16)h;
                }
            }
        }
    }

    // layer 1
    {
        f16x8 bf[4][2];
        float bia[4];
#pragma unroll
        for (int nt = 0; nt < 4; ++nt) {
            bf[nt][0] = *(const f16x8*)&w1s[(nt * 16 + lr) * 72 + lg * 8];
            bf[nt][1] = *(const f16x8*)&w1s[(nt * 16 + lr) * 72 + 32 + lg * 8];
            bia[nt] = b1[nt * 16 + lr];
        }
#pragma unroll
        for (int mt = 0; mt < 4; ++mt) {
            f16x8 a0 = *(const f16x8*)&hbuf[(mt * 16 + lr) * 72 + lg * 8];
            f16x8 a1 = *(const f16x8*)&hbuf[(mt * 16 + lr) * 72 + 32 + lg * 8];
#pragma unroll
            for (int nt = 0; nt < 4; ++nt) {
                f32x4 c = {0.f, 0.f, 0.f, 0.f};
                c = __builtin_amdgcn_mfma_f32_16x16x32_f16(a0, bf[nt][0], c, 0, 0, 0);
                c = __builtin_amdgcn_mfma_f32_16x16x32_f16(a1, bf[nt][1], c, 0, 0, 0);
#pragma unroll
                for (int q = 0; q < 4; ++q) {
                    float h = fmaxf(c[q] + bia[nt], 0.f);
                    hbuf[(mt * 16 + lg * 4 + q) * 72 + nt * 16 + lr] = (f16)h;
                }
            }
        }
    }

    // layer 2 -> h output at original positions
    {
        f16x8 bf0 = *(const f16x8*)&w2s[lr * 72 + lg * 8];
        f16x8 bf1 = *(const f16x8*)&w2s[lr * 72 + 32 + lg * 8];
        float bia2 = (lr < 3) ? b2[lr] : 0.f;
#pragma unroll
        for (int mt = 0; mt < 4; ++mt) {
            f16x8 a0 = *(const f16x8*)&hbuf[(mt * 16 + lr) * 72 + lg * 8];
            f16x8 a1 = *(const f16x8*)&hbuf[(mt * 16 + lr) * 72 + 32 + lg * 8];
            f32x4 c = {0.f, 0.f, 0.f, 0.f};
            c = __builtin_amdgcn_mfma_f32_16x16x32_f16(a0, bf0, c, 0, 0, 0);
            c = __builtin_amdgcn_mfma_f32_16x16x32_f16(a1, bf1, c, 0, 0, 0);
            if (lr < 3) {
#pragma unroll
                for (int q = 0; q < 4; ++q) {
                    int row = mt * 16 + lg * 4 + q;
                    int po = pidx ? (int)pidx[gblk + row] : (gblk + row);
                    out[(size_t)po * 3 + lr] = c[q] + bia2;
                }
            }
        }
    }
}

extern "C" void kernel_launch(void* const* d_in, const int* in_sizes, int n_in,
                              void* d_out, int out_size, void* d_ws, size_t ws_size,
                              hipStream_t stream) {
    const float* x    = (const float*)d_in[0];
    const float* cmax = (const float*)d_in[1];
    const float* emb  = (const float*)d_in[2];
    const float* w0   = (const float*)d_in[3];
    const float* b0   = (const float*)d_in[4];
    const float* w1   = (const float*)d_in[5];
    const float* b1   = (const float*)d_in[6];
    const float* w2   = (const float*)d_in[7];
    const float* b2   = (const float*)d_in[8];
    const int npts = in_sizes[0] / 2;
    const int nblk = npts / 256;

    LevelMeta meta;
    const double S = log2(2048.0 / 16.0) / 15.0;
    long long off = 0;
    for (int l = 0; l < NLEV; ++l) {
        double s = pow(2.0, l * S) * 16.0 - 1.0;
        int r = (int)ceil(s) + 1;
        long long pc = (long long)(r + 1) * (r + 1);
        if (pc > (1ll << 24)) pc = (1ll << 24);
        pc = ((pc + 7) / 8) * 8;
        meta.scale[l] = (float)s;
        meta.r1[l]    = r + 1;
        meta.off[l]   = (int)off;
        off += pc;
    }

    // workspace layout
    size_t need = (size_t)NBIN * 4 * 2 + (size_t)npts * 4 + (size_t)npts * 8;
    if (ws_size >= need && (npts & 255) == 0 && (nblk & 7) == 0) {
        unsigned* hist = (unsigned*)d_ws;
        unsigned* base = hist + NBIN;
        unsigned* pidx = base + NBIN;
        float2*   px   = (float2*)(pidx + npts);

        hipLaunchKernelGGL(zero_kernel, dim3(1), dim3(256), 0, stream, hist);
        hipLaunchKernelGGL(hist_kernel, dim3(nblk), dim3(256), 0, stream, x, cmax, hist);
        hipLaunchKernelGGL(scan_kernel, dim3(1), dim3(256), 0, stream, hist, base);
        hipLaunchKernelGGL(scatter_kernel, dim3(nblk), dim3(256), 0, stream, x, cmax, base, pidx, px);
        hipLaunchKernelGGL(hashmlp_kernel, dim3(nblk), dim3(256), 0, stream,
                           x, cmax, pidx, px, emb, w0, b0, w1, b1, w2, b2,
                           (float*)d_out, npts, nblk, meta);
    } else {
        hipLaunchKernelGGL(hashmlp_kernel, dim3(nblk), dim3(256), 0, stream,
                           x, cmax, (const unsigned*)nullptr, (const float2*)nullptr,
                           emb, w0, b0, w1, b1, w2, b2,
                           (float*)d_out, npts, nblk, meta);
    }
}

// Round 4
// 487.954 us; speedup vs baseline: 1.0898x; 1.0736x over previous
//
#include <hip/hip_runtime.h>
#include <math.h>

#define NLEV 16

typedef _Float16 f16;
typedef f16 f16x8 __attribute__((ext_vector_type(8)));
typedef float f32x4 __attribute__((ext_vector_type(4)));

struct LevelMeta {
    float scale[NLEV];
    int   r1[NLEV];    // grid row stride = r+1
    int   off[NLEV];   // element offset into embeddings table
};

// 8B-aligned 4-float chunk (two adjacent float2 corners in one load)
struct alignas(8) F4 { float x, y, z, w; };

// 2D bit-interleave: spread up-to-8-bit v to even bit positions
__device__ inline unsigned spread2d(unsigned v) {
    v = (v | (v << 4)) & 0x0F0Fu;
    v = (v | (v << 2)) & 0x3333u;
    v = (v | (v << 1)) & 0x5555u;
    return v;
}

__device__ inline unsigned bin_of(float x0, float x1, int res) {
    int bx = (int)(x0 * (float)res); bx = bx < 0 ? 0 : (bx > res - 1 ? res - 1 : bx);
    int by = (int)(x1 * (float)res); by = by < 0 ? 0 : (by > res - 1 ? res - 1 : by);
    return spread2d((unsigned)bx) | (spread2d((unsigned)by) << 1);  // [0, res*res)
}

// ---- pass 0: zero the histogram ----
__global__ __launch_bounds__(256)
void zero_kernel(unsigned* __restrict__ hist) {
    ((uint4*)hist)[blockIdx.x * 256 + threadIdx.x] = uint4{0, 0, 0, 0};
}

// ---- pass 1: per-bin histogram ----
__global__ __launch_bounds__(256)
void hist_kernel(const float* __restrict__ x, const float* __restrict__ cmax,
                 unsigned* __restrict__ hist, int res) {
    int p = blockIdx.x * 256 + threadIdx.x;
    float2 xy = ((const float2*)x)[p];
    float x0 = xy.x / cmax[1];
    float x1 = xy.y / cmax[0];
    atomicAdd(&hist[bin_of(x0, x1, res)], 1u);
}

// ---- pass 2: exclusive prefix scan of nbin bins (one block, 256 threads) ----
// nchunk = nbin/1024 uint4s per thread
__global__ __launch_bounds__(256)
void scan_kernel(const unsigned* __restrict__ hist, unsigned* __restrict__ base,
                 int nchunk) {
    __shared__ unsigned wsum[4];
    int t = threadIdx.x;
    const uint4* h4 = (const uint4*)hist;
    unsigned s = 0;
    for (int k = 0; k < nchunk; ++k) {
        uint4 h = h4[t * nchunk + k];
        s += h.x + h.y + h.z + h.w;
    }
    int lane = t & 63, w = t >> 6;
    unsigned xs = s;
#pragma unroll
    for (int off = 1; off < 64; off <<= 1) {
        unsigned y = (unsigned)__shfl_up((int)xs, off);
        if (lane >= off) xs += y;
    }
    if (lane == 63) wsum[w] = xs;
    __syncthreads();
    unsigned wo = 0;
    for (int k = 0; k < w; ++k) wo += wsum[k];
    unsigned run = wo + xs - s;  // exclusive prefix of this thread's chunk
    uint4* b4 = (uint4*)base;
    for (int k = 0; k < nchunk; ++k) {
        uint4 h = h4[t * nchunk + k];
        uint4 b;
        b.x = run;
        b.y = b.x + h.x;
        b.z = b.y + h.y;
        b.w = b.z + h.z;
        run = b.w + h.w;
        b4[t * nchunk + k] = b;
    }
}

// ---- pass 3: scatter into sorted order ----
__global__ __launch_bounds__(256)
void scatter_kernel(const float* __restrict__ x, const float* __restrict__ cmax,
                    unsigned* __restrict__ base, unsigned* __restrict__ pidx,
                    float2* __restrict__ px, int res) {
    int p = blockIdx.x * 256 + threadIdx.x;
    float2 xy = ((const float2*)x)[p];
    float x0 = xy.x / cmax[1];
    float x1 = xy.y / cmax[0];
    unsigned rank = atomicAdd(&base[bin_of(x0, x1, res)], 1u);
    pidx[rank] = (unsigned)p;
    float2 v; v.x = x0; v.y = x1;
    px[rank] = v;
}

// ---- pass 4: fused hashgrid + MLP ----
// LDS: w0s 5120B + w1s 9216B + w2s 2304B + wbuf 36864B = 53504B -> 3 WG/CU
__global__ __launch_bounds__(256, 3)
void hashmlp_kernel(const float* __restrict__ x,
                    const float* __restrict__ cmax,
                    const unsigned* __restrict__ pidx,   // may be null (fallback)
                    const float2* __restrict__ px,       // may be null
                    const float* __restrict__ emb,
                    const float* __restrict__ w0,
                    const float* __restrict__ b0,
                    const float* __restrict__ w1,
                    const float* __restrict__ b1,
                    const float* __restrict__ w2,
                    const float* __restrict__ b2,
                    float* __restrict__ out,
                    int npts, int nblk,
                    LevelMeta meta)
{
    __shared__ f16 w0s[64 * 40];
    __shared__ f16 w1s[64 * 72];
    __shared__ f16 w2s[16 * 72];
    __shared__ f16 wbuf[4][4608];

    const int tid  = threadIdx.x;
    const int lane = tid & 63;
    const int wave = tid >> 6;

    for (int i = tid; i < 64 * 32; i += 256)
        w0s[(i >> 5) * 40 + (i & 31)] = (f16)w0[i];
    for (int i = tid; i < 64 * 64; i += 256)
        w1s[(i >> 6) * 72 + (i & 63)] = (f16)w1[i];
    for (int i = tid; i < 16 * 64; i += 256) {
        int r = i >> 6, c = i & 63;
        w2s[r * 72 + c] = (r < 3) ? (f16)w2[r * 64 + c] : (f16)0.f;
    }
    __syncthreads();

    // XCD-chunked swizzle: contiguous sorted (spatial) range per XCD
    int bid = blockIdx.x;
    int cpx = nblk >> 3;
    int swz = (bid & 7) * cpx + (bid >> 3);
    const int g = swz * 256 + tid;             // sorted slot
    const int gblk = swz * 256 + wave * 64;    // wave's first sorted slot

    int p;          // original point index (output location)
    float x0, x1;
    if (pidx) {
        p = (int)pidx[g];
        float2 xy = px[g];
        x0 = xy.x; x1 = xy.y;
    } else {
        p = g;
        float2 xy = ((const float2*)x)[p];
        x0 = xy.x / cmax[1];
        x1 = xy.y / cmax[0];
    }

    float fr[32];
#pragma unroll
    for (int l = 0; l < NLEV; ++l) {
        const float sc = meta.scale[l];
        const int r1 = meta.r1[l];
        const int off = meta.off[l];
        float p0 = x0 * sc + 0.5f;
        float p1 = x1 * sc + 0.5f;
        float g0 = floorf(p0), g1 = floorf(p1);
        float f0 = p0 - g0, f1 = p1 - g1;
        int i0 = (int)g0, i1 = (int)g1;
        const float* ebf = emb + 2 * (off + i1 * r1 + i0);
        F4 lo = *(const F4*)ebf;              // e00.x e00.y e10.x e10.y
        F4 hi = *(const F4*)(ebf + 2 * r1);   // e01.x e01.y e11.x e11.y
        float omf0 = 1.f - f0, omf1 = 1.f - f1;
        float w00 = omf0 * omf1, w01 = omf0 * f1, w10 = f0 * omf1, w11 = f0 * f1;
        float a0 = w00 * lo.x; a0 += w01 * hi.x; a0 += w10 * lo.z; a0 += w11 * hi.z;
        float a1 = w00 * lo.y; a1 += w01 * hi.y; a1 += w10 * lo.w; a1 += w11 * hi.w;
        fr[2 * l]     = a0;
        fr[2 * l + 1] = a1;
    }

    // out_lc0 (fp32, exact) at original position
    float* outlc = out + (size_t)npts * 3 + (size_t)p * 32;
#pragma unroll
    for (int c = 0; c < 8; ++c) {
        float4 v;
        v.x = fr[4 * c]; v.y = fr[4 * c + 1]; v.z = fr[4 * c + 2]; v.w = fr[4 * c + 3];
        ((float4*)outlc)[c] = v;
    }

    // stage relu(feats)*2^14 as f16 into per-wave LDS [64][40]
    f16* fbuf = wbuf[wave];
#pragma unroll
    for (int c = 0; c < 4; ++c) {
        f16x8 v;
#pragma unroll
        for (int j = 0; j < 8; ++j)
            v[j] = (f16)(fmaxf(fr[8 * c + j], 0.f) * 16384.f);
        *(f16x8*)&fbuf[lane * 40 + c * 8] = v;
    }

    const int lr = lane & 15;
    const int lg = lane >> 4;
    f16* hbuf = wbuf[wave];

    // layer 0
    {
        f16x8 bf[4];
        float bia[4];
#pragma unroll
        for (int nt = 0; nt < 4; ++nt) {
            bf[nt] = *(const f16x8*)&w0s[(nt * 16 + lr) * 40 + lg * 8];
            bia[nt] = b0[nt * 16 + lr];
        }
#pragma unroll
        for (int mt = 3; mt >= 0; --mt) {
            f16x8 a = *(const f16x8*)&fbuf[(mt * 16 + lr) * 40 + lg * 8];
#pragma unroll
            for (int nt = 0; nt < 4; ++nt) {
                f32x4 c = {0.f, 0.f, 0.f, 0.f};
                c = __builtin_amdgcn_mfma_f32_16x16x32_f16(a, bf[nt], c, 0, 0, 0);
#pragma unroll
                for (int q = 0; q < 4; ++q) {
                    float h = fmaxf(c[q] * (1.0f / 16384.f) + bia[nt], 0.f);
                    hbuf[(mt * 16 + lg * 4 + q) * 72 + nt * 16 + lr] = (f16)h;
                }
            }
        }
    }

    // layer 1
    {
        f16x8 bf[4][2];
        float bia[4];
#pragma unroll
        for (int nt = 0; nt < 4; ++nt) {
            bf[nt][0] = *(const f16x8*)&w1s[(nt * 16 + lr) * 72 + lg * 8];
            bf[nt][1] = *(const f16x8*)&w1s[(nt * 16 + lr) * 72 + 32 + lg * 8];
            bia[nt] = b1[nt * 16 + lr];
        }
#pragma unroll
        for (int mt = 0; mt < 4; ++mt) {
            f16x8 a0 = *(const f16x8*)&hbuf[(mt * 16 + lr) * 72 + lg * 8];
            f16x8 a1 = *(const f16x8*)&hbuf[(mt * 16 + lr) * 72 + 32 + lg * 8];
#pragma unroll
            for (int nt = 0; nt < 4; ++nt) {
                f32x4 c = {0.f, 0.f, 0.f, 0.f};
                c = __builtin_amdgcn_mfma_f32_16x16x32_f16(a0, bf[nt][0], c, 0, 0, 0);
                c = __builtin_amdgcn_mfma_f32_16x16x32_f16(a1, bf[nt][1], c, 0, 0, 0);
#pragma unroll
                for (int q = 0; q < 4; ++q) {
                    float h = fmaxf(c[q] + bia[nt], 0.f);
                    hbuf[(mt * 16 + lg * 4 + q) * 72 + nt * 16 + lr] = (f16)h;
                }
            }
        }
    }

    // layer 2 -> h output at original positions
    {
        f16x8 bf0 = *(const f16x8*)&w2s[lr * 72 + lg * 8];
        f16x8 bf1 = *(const f16x8*)&w2s[lr * 72 + 32 + lg * 8];
        float bia2 = (lr < 3) ? b2[lr] : 0.f;
#pragma unroll
        for (int mt = 0; mt < 4; ++mt) {
            f16x8 a0 = *(const f16x8*)&hbuf[(mt * 16 + lr) * 72 + lg * 8];
            f16x8 a1 = *(const f16x8*)&hbuf[(mt * 16 + lr) * 72 + 32 + lg * 8];
            f32x4 c = {0.f, 0.f, 0.f, 0.f};
            c = __builtin_amdgcn_mfma_f32_16x16x32_f16(a0, bf0, c, 0, 0, 0);
            c = __builtin_amdgcn_mfma_f32_16x16x32_f16(a1, bf1, c, 0, 0, 0);
            if (lr < 3) {
#pragma unroll
                for (int q = 0; q < 4; ++q) {
                    int row = mt * 16 + lg * 4 + q;
                    int po = pidx ? (int)pidx[gblk + row] : (gblk + row);
                    out[(size_t)po * 3 + lr] = c[q] + bia2;
                }
            }
        }
    }
}

extern "C" void kernel_launch(void* const* d_in, const int* in_sizes, int n_in,
                              void* d_out, int out_size, void* d_ws, size_t ws_size,
                              hipStream_t stream) {
    const float* x    = (const float*)d_in[0];
    const float* cmax = (const float*)d_in[1];
    const float* emb  = (const float*)d_in[2];
    const float* w0   = (const float*)d_in[3];
    const float* b0   = (const float*)d_in[4];
    const float* w1   = (const float*)d_in[5];
    const float* b1   = (const float*)d_in[6];
    const float* w2   = (const float*)d_in[7];
    const float* b2   = (const float*)d_in[8];
    const int npts = in_sizes[0] / 2;
    const int nblk = npts / 256;

    LevelMeta meta;
    const double S = log2(2048.0 / 16.0) / 15.0;
    long long off = 0;
    for (int l = 0; l < NLEV; ++l) {
        double s = pow(2.0, l * S) * 16.0 - 1.0;
        int r = (int)ceil(s) + 1;
        long long pc = (long long)(r + 1) * (r + 1);
        if (pc > (1ll << 24)) pc = (1ll << 24);
        pc = ((pc + 7) / 8) * 8;
        meta.scale[l] = (float)s;
        meta.r1[l]    = r + 1;
        meta.off[l]   = (int)off;
        off += pc;
    }

    // pick bin resolution by workspace size (bigger = less atomic contention)
    int res = 0, nbin = 0;
    size_t need_big   = (size_t)65536 * 8 + (size_t)npts * 12;
    size_t need_small = (size_t)4096  * 8 + (size_t)npts * 12;
    if (ws_size >= need_big)        { res = 256; nbin = 65536; }
    else if (ws_size >= need_small) { res = 64;  nbin = 4096;  }

    if (nbin && (npts & 255) == 0 && (nblk & 7) == 0) {
        unsigned* hist = (unsigned*)d_ws;
        unsigned* base = hist + nbin;
        unsigned* pidx = base + nbin;
        float2*   px   = (float2*)(pidx + npts);

        hipLaunchKernelGGL(zero_kernel, dim3(nbin / 1024), dim3(256), 0, stream, hist);
        hipLaunchKernelGGL(hist_kernel, dim3(nblk), dim3(256), 0, stream, x, cmax, hist, res);
        hipLaunchKernelGGL(scan_kernel, dim3(1), dim3(256), 0, stream, hist, base, nbin / 1024);
        hipLaunchKernelGGL(scatter_kernel, dim3(nblk), dim3(256), 0, stream, x, cmax, base, pidx, px, res);
        hipLaunchKernelGGL(hashmlp_kernel, dim3(nblk), dim3(256), 0, stream,
                           x, cmax, pidx, px, emb, w0, b0, w1, b1, w2, b2,
                           (float*)d_out, npts, nblk, meta);
    } else {
        hipLaunchKernelGGL(hashmlp_kernel, dim3(nblk), dim3(256), 0, stream,
                           x, cmax, (const unsigned*)nullptr, (const float2*)nullptr,
                           emb, w0, b0, w1, b1, w2, b2,
                           (float*)d_out, npts, nblk, meta);
    }
}